// Round 2
// baseline (3042.295 us; speedup 1.0000x reference)
//
#include <hip/hip_runtime.h>
#include <math.h>

#define PI_D 3.14159265358979323846

// ---------------- tables ----------------
__global__ void k_tables(float* tzf, float* tzi, float* txf, float* txi) {
    int t = blockIdx.x * blockDim.x + threadIdx.x;
    if (t < 320) {
        int z = t >> 3, k = t & 7;
        double ang = -2.0 * PI_D * (double)(z * k) / 40.0;
        tzf[t * 2] = (float)cos(ang); tzf[t * 2 + 1] = (float)sin(ang);
        tzi[t * 2] = (float)cos(-ang); tzi[t * 2 + 1] = (float)sin(-ang);
    }
    if (t < 1472) {
        int xx = t / 23, m = t % 23;
        double ang = -2.0 * PI_D * (double)(xx * (m - 11)) / 64.0;
        txf[t * 2] = (float)cos(ang); txf[t * 2 + 1] = (float)sin(ang);
        txi[t * 2] = (float)cos(-ang); txi[t * 2 + 1] = (float)sin(-ang);
    }
}

// transpose mlp_w2 and w_w for all 4 layers: w2t[l][j][o] = w2[l][o][j]
__global__ void k_wtrans(const float* __restrict__ w2, const float* __restrict__ ww,
                         float* __restrict__ w2t, float* __restrict__ wwt) {
    int gid = blockIdx.x * blockDim.x + threadIdx.x;
    if (gid < 16384) {
        int l = gid >> 12, r = gid & 4095, o = r >> 6, i = r & 63;
        w2t[l * 4096 + i * 64 + o] = w2[l * 4096 + o * 64 + i];
        wwt[l * 4096 + i * 64 + o] = ww[l * 4096 + o * 64 + i];
    }
}

// ---------------- lift ----------------
__global__ void k_lift(const float* __restrict__ xin, const float* __restrict__ pw,
                       const float* __restrict__ pb, float* __restrict__ xo) {
    int gid = blockIdx.x * 256 + threadIdx.x;   // 327680 total
    int b = gid / 163840, p = gid % 163840;
    int y = p / 2560, xx = (p / 40) % 64, z = p % 40;
    float v[13];
#pragma unroll
    for (int i = 0; i < 10; i++) v[i] = xin[(size_t)gid * 10 + i];
    v[10] = (float)((double)y / 63.0);
    v[11] = (float)((double)xx / 63.0);
    v[12] = (float)((double)z / 39.0);
    size_t ob = (size_t)b * 10485760 + p;
    for (int c = 0; c < 64; c++) {
        float a = pb[c];
#pragma unroll
        for (int i = 0; i < 13; i++) a += pw[c * 13 + i] * v[i];
        xo[ob + (size_t)c * 163840] = a;
    }
}

// ---------------- forward z-DFT (r2c, 8 modes) fused with x-DFT (64 -> 23 modes) ----
// grid: (b,c,y) = 8192 blocks, 256 threads. out: Fx[b][c][y][m(23)][k(8)][2]
__global__ void k_fwd_zx(const float* __restrict__ x, const float* __restrict__ tzf,
                         const float* __restrict__ txf, float* __restrict__ Fx) {
    int bid = blockIdx.x;
    int b = bid >> 12, c = (bid >> 6) & 63, y = bid & 63;
    int t = threadIdx.x;
    __shared__ float xr_[2560];
    __shared__ float f1[1024];
    __shared__ float tzs[640];
    const float* xrow = x + ((size_t)((b * 64 + c) * 4096 + y * 64)) * 40;
    for (int idx = t; idx < 2560; idx += 256) xr_[idx] = xrow[idx];
    for (int idx = t; idx < 640; idx += 256) tzs[idx] = tzf[idx];
    __syncthreads();
    for (int q = t; q < 512; q += 256) {
        int xx = q >> 3, k = q & 7;
        float sr = 0.f, si = 0.f;
        for (int z = 0; z < 40; z++) {
            float v = xr_[xx * 40 + z];
            sr += v * tzs[(z * 8 + k) * 2];
            si += v * tzs[(z * 8 + k) * 2 + 1];
        }
        f1[(xx * 8 + k) * 2] = sr;
        f1[(xx * 8 + k) * 2 + 1] = si;
    }
    __syncthreads();
    if (t < 184) {
        int m = t >> 3, k = t & 7;
        float sr = 0.f, si = 0.f;
        for (int xx = 0; xx < 64; xx++) {
            float ar = f1[(xx * 8 + k) * 2], ai = f1[(xx * 8 + k) * 2 + 1];
            float tr = txf[(xx * 23 + m) * 2], ti = txf[(xx * 23 + m) * 2 + 1];
            sr += ar * tr - ai * ti;
            si += ar * ti + ai * tr;
        }
        size_t g = ((size_t)(((b * 64 + c) * 64 + y) * 23 + m) * 8 + k) * 2;
        Fx[g] = sr; Fx[g + 1] = si;
    }
}

// ---------------- forward y-DFT (64 -> 23 modes) ----------------
// grid (b,c,m) = 2944 blocks, 192 threads. out: Xs[b][c][n(23)][m][k][2]
__global__ void k_fwd_y(const float* __restrict__ Fx, const float* __restrict__ txf,
                        float* __restrict__ Xs) {
    int bid = blockIdx.x;
    int b = bid / 1472, rem = bid % 1472, c = rem / 23, m = rem % 23;
    int t = threadIdx.x;
    __shared__ float s[1024];  // [y][k][2]
    for (int idx = t; idx < 512; idx += 192) {
        int y = idx >> 3, k = idx & 7;
        size_t g = ((size_t)(((b * 64 + c) * 64 + y) * 23 + m) * 8 + k) * 2;
        s[idx * 2] = Fx[g]; s[idx * 2 + 1] = Fx[g + 1];
    }
    __syncthreads();
    if (t < 184) {
        int n = t >> 3, k = t & 7;
        float sr = 0.f, si = 0.f;
        for (int y = 0; y < 64; y++) {
            float ar = s[(y * 8 + k) * 2], ai = s[(y * 8 + k) * 2 + 1];
            float tr = txf[(y * 23 + n) * 2], ti = txf[(y * 23 + n) * 2 + 1];
            sr += ar * tr - ai * ti;
            si += ar * ti + ai * tr;
        }
        size_t g = ((size_t)(((b * 64 + c) * 23 + n) * 23 + m) * 8 + k) * 2;
        Xs[g] = sr; Xs[g + 1] = si;
    }
}

// ---------------- mode mixing with on-the-fly radial-weight gather ----------------
// grid 529 = (n,m), block 512 = (o, t). both batches per block.
__global__ void k_mix(const float* __restrict__ Xs, const float* __restrict__ WLC,
                      const float* __restrict__ WLR, float* __restrict__ Md) {
    int bid = blockIdx.x;
    int n = bid / 23, m = bid % 23;
    int a = n, c = m, yy, w;
    if (c >= 11) { yy = a; w = c - 11; } else { yy = 22 - a; w = 11 - c; }
    int isLC, idx;
    if (yy >= 12) {
        int p = yy - 12, q = w;
        if (q == 0) { isLC = 1; idx = p + 1; } else { isLC = 0; idx = p * 11 + (q - 1); }
    } else {
        if (w == 0) { isLC = 1; idx = 11 - yy; }
        else {
            int p = w - 1, q = 11 - yy;
            if (q == 0) { isLC = 1; idx = p + 1; } else { isLC = 0; idx = p * 11 + (q - 1); }
        }
    }
    const float* src = isLC ? WLC : WLR;
    int stride = isLC ? 96 : 968;
    int base8 = idx * 8;

    int t = threadIdx.x;
    int o = t >> 3, tt = t & 7;
    __shared__ __align__(16) float wl[8 * 64 * 8];
    __shared__ float xl[256];
    float aR0 = 0.f, aI0 = 0.f, aR1 = 0.f, aI1 = 0.f;
    for (int i0 = 0; i0 < 64; i0 += 8) {
        {
            int il = t >> 6, oo = t & 63;
            const float4* g = (const float4*)(src + (size_t)((i0 + il) * 64 + oo) * stride + base8);
            float4 A = g[0], B = g[1];
            float4* d = (float4*)&wl[(il * 64 + oo) * 8];
            d[0] = A; d[1] = B;
        }
        if (t < 256) {
            int bb = t >> 7, il = (t >> 4) & 7, kk = (t >> 1) & 7, ri = t & 1;
            xl[t] = Xs[((size_t)(((bb * 64 + i0 + il) * 23 + n) * 23 + m) * 8 + kk) * 2 + ri];
        }
        __syncthreads();
#pragma unroll
        for (int il = 0; il < 8; il++) {
            float wv = wl[(il * 64 + o) * 8 + tt];
            float xr0 = xl[(il * 8 + tt) * 2], xi0 = xl[(il * 8 + tt) * 2 + 1];
            float xr1 = xl[128 + (il * 8 + tt) * 2], xi1 = xl[128 + (il * 8 + tt) * 2 + 1];
            aR0 += wv * xr0; aI0 += wv * xi0;
            aR1 += wv * xr1; aI1 += wv * xi1;
        }
        __syncthreads();
    }
    size_t ob0 = ((size_t)((o * 23 + n) * 23 + m) * 8 + tt) * 2;
    size_t ob1 = ((size_t)(((64 + o) * 23 + n) * 23 + m) * 8 + tt) * 2;
    Md[ob0] = aR0; Md[ob0 + 1] = aI0;
    Md[ob1] = aR1; Md[ob1 + 1] = aI1;
}

// ---------------- inverse y (23 -> 64) ----------------
__global__ void k_inv_y(const float* __restrict__ Md, const float* __restrict__ txi,
                        float* __restrict__ T1) {
    int bid = blockIdx.x;
    int b = bid / 1472, rem = bid % 1472, o = rem / 23, m = rem % 23;
    int t = threadIdx.x;
    __shared__ float s[368];  // [n][k][2]
    if (t < 184) {
        int n = t >> 3, kk = t & 7;
        size_t g = ((size_t)(((b * 64 + o) * 23 + n) * 23 + m) * 8 + kk) * 2;
        s[t * 2] = Md[g]; s[t * 2 + 1] = Md[g + 1];
    }
    __syncthreads();
    int y = t >> 3, k = t & 7;
    float sr = 0.f, si = 0.f;
    for (int n = 0; n < 23; n++) {
        float ar = s[(n * 8 + k) * 2], ai = s[(n * 8 + k) * 2 + 1];
        float tr = txi[(y * 23 + n) * 2], ti = txi[(y * 23 + n) * 2 + 1];
        sr += ar * tr - ai * ti;
        si += ar * ti + ai * tr;
    }
    size_t g = ((size_t)(((b * 64 + o) * 64 + y) * 23 + m) * 8 + k) * 2;
    T1[g] = sr; T1[g + 1] = si;
}

// ---------------- inverse x (23 -> 64) ----------------
__global__ void k_inv_x(const float* __restrict__ T1, const float* __restrict__ txi,
                        float* __restrict__ T2) {
    int bid = blockIdx.x;
    int b = bid >> 12, o = (bid >> 6) & 63, y = bid & 63;
    int t = threadIdx.x;
    __shared__ float s[368];  // [m][k][2]
    if (t < 184) {
        size_t g = (size_t)(((b * 64 + o) * 64 + y)) * 368 + t * 2;
        s[t * 2] = T1[g]; s[t * 2 + 1] = T1[g + 1];
    }
    __syncthreads();
    int xx = t >> 3, k = t & 7;
    float sr = 0.f, si = 0.f;
    for (int m = 0; m < 23; m++) {
        float ar = s[(m * 8 + k) * 2], ai = s[(m * 8 + k) * 2 + 1];
        float tr = txi[(xx * 23 + m) * 2], ti = txi[(xx * 23 + m) * 2 + 1];
        sr += ar * tr - ai * ti;
        si += ar * ti + ai * tr;
    }
    size_t g = ((size_t)((b * 64 + o) * 4096 + y * 64 + xx) * 8 + k) * 2;
    T2[g] = sr; T2[g + 1] = si;
}

// ---------------- fused c2r inverse-z + MLP + skip + relu ----------------
__device__ __forceinline__ float gelu_exact(float h) {
    return 0.5f * h * (1.0f + erff(h * 0.70710678118654752f));
}

// grid (b,y,xg) = 1024 blocks, 320 threads = 8 cols x 40 z
// __launch_bounds__(320, 2): allow up to 256 VGPRs so x1[64]+outv[64] stay in
// registers (default allocator picked 76 VGPRs -> massive scratch spill,
// VALUBusy 20%).
__global__ __launch_bounds__(320, 2) void k_fused(
    const float* __restrict__ t2buf, const float* __restrict__ xcur,
    const float* __restrict__ w1, const float* __restrict__ b1,
    const float* __restrict__ w2t, const float* __restrict__ b2,
    const float* __restrict__ wwt, const float* __restrict__ wb,
    const float* __restrict__ tzi, float* __restrict__ xnext, int dorelu) {
    int bid = blockIdx.x;
    int b = bid >> 9, y = (bid >> 3) & 63, xg = bid & 7;
    int t = threadIdx.x;
    int col = t / 40, z = t % 40;
    // pad rows to 1028 floats (16B-aligned) for float4/ds_read_b128 access
    __shared__ __align__(16) float t2s[8 * 1028];
    size_t gbase = (size_t)b * 4194304 + (size_t)(y * 64 + xg * 8) * 16;
    // 2048 float4 elements to stage
    for (int idx = t; idx < 2048; idx += 320) {
        int o = idx >> 5, cl = (idx >> 2) & 7, q = idx & 3;
        const float4* gp = (const float4*)(t2buf + gbase + (size_t)o * 65536 + cl * 16 + q * 4);
        *(float4*)&t2s[cl * 1028 + o * 16 + q * 4] = *gp;
    }
    __syncthreads();
    float ck[8], sk[8];
#pragma unroll
    for (int k = 0; k < 8; k++) {
        ck[k] = tzi[(z * 8 + k) * 2];
        sk[k] = tzi[(z * 8 + k) * 2 + 1];
    }
    const float scale = 1.0f / 163840.0f;
    float x1[64];
    const float* tb = &t2s[col * 1028];
#pragma unroll 4
    for (int i = 0; i < 64; i++) {
        float4 r0 = *(const float4*)&tb[i * 16];
        float4 r1 = *(const float4*)&tb[i * 16 + 4];
        float4 r2 = *(const float4*)&tb[i * 16 + 8];
        float4 r3 = *(const float4*)&tb[i * 16 + 12];
        // r0 = {Re0, Im0, Re1, Im1}, ... ; Im of DC dropped (pocketfft c2r)
        float acc = r0.x;
        acc += 2.0f * (r0.z * ck[1] - r0.w * sk[1]);
        acc += 2.0f * (r1.x * ck[2] - r1.y * sk[2]);
        acc += 2.0f * (r1.z * ck[3] - r1.w * sk[3]);
        acc += 2.0f * (r2.x * ck[4] - r2.y * sk[4]);
        acc += 2.0f * (r2.z * ck[5] - r2.w * sk[5]);
        acc += 2.0f * (r3.x * ck[6] - r3.y * sk[6]);
        acc += 2.0f * (r3.z * ck[7] - r3.w * sk[7]);
        x1[i] = acc * scale;
    }
    float outv[64];
#pragma unroll
    for (int o = 0; o < 64; o++) outv[o] = b2[o] + wb[o];
#pragma unroll 2
    for (int j = 0; j < 64; j++) {
        float hj = b1[j];
#pragma unroll
        for (int i = 0; i < 64; i++) hj += w1[j * 64 + i] * x1[i];
        float g = gelu_exact(hj);
#pragma unroll
        for (int o = 0; o < 64; o++) outv[o] += w2t[j * 64 + o] * g;
    }
    size_t sb = (size_t)b * 10485760 + (size_t)(y * 64 + xg * 8) * 40;
    int poff = col * 40 + z;
#pragma unroll 2
    for (int i = 0; i < 64; i++) {
        float xi = xcur[sb + (size_t)i * 163840 + poff];
#pragma unroll
        for (int o = 0; o < 64; o++) outv[o] += wwt[i * 64 + o] * xi;
    }
#pragma unroll
    for (int o = 0; o < 64; o++) {
        float v = outv[o];
        if (dorelu) v = fmaxf(v, 0.0f);
        xnext[sb + (size_t)o * 163840 + poff] = v;
    }
}

// ---------------- final head: mlp3d with q weights ----------------
__global__ __launch_bounds__(256, 2) void k_head(
    const float* __restrict__ xcur,
    const float* __restrict__ qw1, const float* __restrict__ qb1,
    const float* __restrict__ qw2, const float* __restrict__ qb2,
    float* __restrict__ outp) {
    int gid = blockIdx.x * 256 + threadIdx.x;  // 327680
    int b = gid / 163840, p = gid % 163840;
    float xv[64];
    size_t base = (size_t)b * 10485760 + p;
#pragma unroll
    for (int i = 0; i < 64; i++) xv[i] = xcur[base + (size_t)i * 163840];
    float acc = qb2[0];
    for (int j = 0; j < 256; j++) {
        float h = qb1[j];
#pragma unroll
        for (int i = 0; i < 64; i++) h += qw1[j * 64 + i] * xv[i];
        acc += qw2[j] * gelu_exact(h);
    }
    outp[gid] = acc;
}

extern "C" void kernel_launch(void* const* d_in, const int* in_sizes, int n_in,
                              void* d_out, int out_size, void* d_ws, size_t ws_size,
                              hipStream_t stream) {
    const float* x_in = (const float*)d_in[0];
    const float* p_w  = (const float*)d_in[1];
    const float* p_b  = (const float*)d_in[2];
    const float* W_LC = (const float*)d_in[3];
    const float* W_LR = (const float*)d_in[4];
    const float* m_w1 = (const float*)d_in[5];
    const float* m_b1 = (const float*)d_in[6];
    const float* m_w2 = (const float*)d_in[7];
    const float* m_b2 = (const float*)d_in[8];
    const float* w_w  = (const float*)d_in[9];
    const float* w_b  = (const float*)d_in[10];
    const float* q_w1 = (const float*)d_in[11];
    const float* q_b1 = (const float*)d_in[12];
    const float* q_w2 = (const float*)d_in[13];
    const float* q_b2 = (const float*)d_in[14];

    char* ws = (char*)d_ws;
    float* tzf = (float*)(ws + 0);
    float* tzi = (float*)(ws + 4096);
    float* txf = (float*)(ws + 8192);
    float* txi = (float*)(ws + 20480);
    float* w2t = (float*)(ws + 32768);
    float* wwt = (float*)(ws + 32768 + 65536);
    size_t off = 32768 + 131072;
    float* xA = (float*)(ws + off); off += 83886080ull;
    float* xB = (float*)(ws + off); off += 83886080ull;
    float* Fx = (float*)(ws + off); off += 12058624ull;
    float* Xs = (float*)(ws + off); off += 4333568ull;
    float* Md = (float*)(ws + off); off += 4333568ull;
    float* T1 = (float*)(ws + off); off += 12058624ull;
    float* T2 = (float*)(ws + off); off += 33554432ull;

    k_tables<<<6, 256, 0, stream>>>(tzf, tzi, txf, txi);
    k_wtrans<<<64, 256, 0, stream>>>(m_w2, w_w, w2t, wwt);
    k_lift<<<1280, 256, 0, stream>>>(x_in, p_w, p_b, xA);

    float* xc = xA;
    float* xn = xB;
    for (int l = 0; l < 4; l++) {
        k_fwd_zx<<<8192, 256, 0, stream>>>(xc, tzf, txf, Fx);
        k_fwd_y<<<2944, 192, 0, stream>>>(Fx, txf, Xs);
        k_mix<<<529, 512, 0, stream>>>(Xs, W_LC + (size_t)l * 393216,
                                       W_LR + (size_t)l * 3964928, Md);
        k_inv_y<<<2944, 512, 0, stream>>>(Md, txi, T1);
        k_inv_x<<<8192, 512, 0, stream>>>(T1, txi, T2);
        k_fused<<<1024, 320, 0, stream>>>(T2, xc, m_w1 + (size_t)l * 4096, m_b1 + l * 64,
                                          w2t + (size_t)l * 4096, m_b2 + l * 64,
                                          wwt + (size_t)l * 4096, w_b + l * 64,
                                          tzi, xn, (l < 3) ? 1 : 0);
        float* tmp = xc; xc = xn; xn = tmp;
    }
    k_head<<<1280, 256, 0, stream>>>(xc, q_w1, q_b1, q_w2, q_b2, (float*)d_out);
}

// Round 3
// 1827.058 us; speedup vs baseline: 1.6651x; 1.6651x over previous
//
#include <hip/hip_runtime.h>
#include <math.h>

#define PI_D 3.14159265358979323846

// ---------------- tables ----------------
__global__ void k_tables(float* tzf, float* tzi, float* txf, float* txi) {
    int t = blockIdx.x * blockDim.x + threadIdx.x;
    if (t < 320) {
        int z = t >> 3, k = t & 7;
        double ang = -2.0 * PI_D * (double)(z * k) / 40.0;
        tzf[t * 2] = (float)cos(ang); tzf[t * 2 + 1] = (float)sin(ang);
        tzi[t * 2] = (float)cos(-ang); tzi[t * 2 + 1] = (float)sin(-ang);
    }
    if (t < 1472) {
        int xx = t / 23, m = t % 23;
        double ang = -2.0 * PI_D * (double)(xx * (m - 11)) / 64.0;
        txf[t * 2] = (float)cos(ang); txf[t * 2 + 1] = (float)sin(ang);
        txi[t * 2] = (float)cos(-ang); txi[t * 2 + 1] = (float)sin(-ang);
    }
}

// transpose mlp_w2 and w_w for all 4 layers: w2t[l][j][o] = w2[l][o][j]
__global__ void k_wtrans(const float* __restrict__ w2, const float* __restrict__ ww,
                         float* __restrict__ w2t, float* __restrict__ wwt) {
    int gid = blockIdx.x * blockDim.x + threadIdx.x;
    if (gid < 16384) {
        int l = gid >> 12, r = gid & 4095, o = r >> 6, i = r & 63;
        w2t[l * 4096 + i * 64 + o] = w2[l * 4096 + o * 64 + i];
        wwt[l * 4096 + i * 64 + o] = ww[l * 4096 + o * 64 + i];
    }
}

// ---------------- lift ----------------
__global__ void k_lift(const float* __restrict__ xin, const float* __restrict__ pw,
                       const float* __restrict__ pb, float* __restrict__ xo) {
    int gid = blockIdx.x * 256 + threadIdx.x;   // 327680 total
    int b = gid / 163840, p = gid % 163840;
    int y = p / 2560, xx = (p / 40) % 64, z = p % 40;
    float v[13];
#pragma unroll
    for (int i = 0; i < 10; i++) v[i] = xin[(size_t)gid * 10 + i];
    v[10] = (float)((double)y / 63.0);
    v[11] = (float)((double)xx / 63.0);
    v[12] = (float)((double)z / 39.0);
    size_t ob = (size_t)b * 10485760 + p;
    for (int c = 0; c < 64; c++) {
        float a = pb[c];
#pragma unroll
        for (int i = 0; i < 13; i++) a += pw[c * 13 + i] * v[i];
        xo[ob + (size_t)c * 163840] = a;
    }
}

// ---------------- forward z-DFT (r2c, 8 modes) fused with x-DFT (64 -> 23 modes) ----
__global__ void k_fwd_zx(const float* __restrict__ x, const float* __restrict__ tzf,
                         const float* __restrict__ txf, float* __restrict__ Fx) {
    int bid = blockIdx.x;
    int b = bid >> 12, c = (bid >> 6) & 63, y = bid & 63;
    int t = threadIdx.x;
    __shared__ float xr_[2560];
    __shared__ float f1[1024];
    __shared__ float tzs[640];
    const float* xrow = x + ((size_t)((b * 64 + c) * 4096 + y * 64)) * 40;
    for (int idx = t; idx < 2560; idx += 256) xr_[idx] = xrow[idx];
    for (int idx = t; idx < 640; idx += 256) tzs[idx] = tzf[idx];
    __syncthreads();
    for (int q = t; q < 512; q += 256) {
        int xx = q >> 3, k = q & 7;
        float sr = 0.f, si = 0.f;
        for (int z = 0; z < 40; z++) {
            float v = xr_[xx * 40 + z];
            sr += v * tzs[(z * 8 + k) * 2];
            si += v * tzs[(z * 8 + k) * 2 + 1];
        }
        f1[(xx * 8 + k) * 2] = sr;
        f1[(xx * 8 + k) * 2 + 1] = si;
    }
    __syncthreads();
    if (t < 184) {
        int m = t >> 3, k = t & 7;
        float sr = 0.f, si = 0.f;
        for (int xx = 0; xx < 64; xx++) {
            float ar = f1[(xx * 8 + k) * 2], ai = f1[(xx * 8 + k) * 2 + 1];
            float tr = txf[(xx * 23 + m) * 2], ti = txf[(xx * 23 + m) * 2 + 1];
            sr += ar * tr - ai * ti;
            si += ar * ti + ai * tr;
        }
        size_t g = ((size_t)(((b * 64 + c) * 64 + y) * 23 + m) * 8 + k) * 2;
        Fx[g] = sr; Fx[g + 1] = si;
    }
}

// ---------------- forward y-DFT (64 -> 23 modes) ----------------
__global__ void k_fwd_y(const float* __restrict__ Fx, const float* __restrict__ txf,
                        float* __restrict__ Xs) {
    int bid = blockIdx.x;
    int b = bid / 1472, rem = bid % 1472, c = rem / 23, m = rem % 23;
    int t = threadIdx.x;
    __shared__ float s[1024];  // [y][k][2]
    for (int idx = t; idx < 512; idx += 192) {
        int y = idx >> 3, k = idx & 7;
        size_t g = ((size_t)(((b * 64 + c) * 64 + y) * 23 + m) * 8 + k) * 2;
        s[idx * 2] = Fx[g]; s[idx * 2 + 1] = Fx[g + 1];
    }
    __syncthreads();
    if (t < 184) {
        int n = t >> 3, k = t & 7;
        float sr = 0.f, si = 0.f;
        for (int y = 0; y < 64; y++) {
            float ar = s[(y * 8 + k) * 2], ai = s[(y * 8 + k) * 2 + 1];
            float tr = txf[(y * 23 + n) * 2], ti = txf[(y * 23 + n) * 2 + 1];
            sr += ar * tr - ai * ti;
            si += ar * ti + ai * tr;
        }
        size_t g = ((size_t)(((b * 64 + c) * 23 + n) * 23 + m) * 8 + k) * 2;
        Xs[g] = sr; Xs[g + 1] = si;
    }
}

// ---------------- mode mixing with on-the-fly radial-weight gather ----------------
__global__ void k_mix(const float* __restrict__ Xs, const float* __restrict__ WLC,
                      const float* __restrict__ WLR, float* __restrict__ Md) {
    int bid = blockIdx.x;
    int n = bid / 23, m = bid % 23;
    int a = n, c = m, yy, w;
    if (c >= 11) { yy = a; w = c - 11; } else { yy = 22 - a; w = 11 - c; }
    int isLC, idx;
    if (yy >= 12) {
        int p = yy - 12, q = w;
        if (q == 0) { isLC = 1; idx = p + 1; } else { isLC = 0; idx = p * 11 + (q - 1); }
    } else {
        if (w == 0) { isLC = 1; idx = 11 - yy; }
        else {
            int p = w - 1, q = 11 - yy;
            if (q == 0) { isLC = 1; idx = p + 1; } else { isLC = 0; idx = p * 11 + (q - 1); }
        }
    }
    const float* src = isLC ? WLC : WLR;
    int stride = isLC ? 96 : 968;
    int base8 = idx * 8;

    int t = threadIdx.x;
    int o = t >> 3, tt = t & 7;
    __shared__ __align__(16) float wl[8 * 64 * 8];
    __shared__ float xl[256];
    float aR0 = 0.f, aI0 = 0.f, aR1 = 0.f, aI1 = 0.f;
    for (int i0 = 0; i0 < 64; i0 += 8) {
        {
            int il = t >> 6, oo = t & 63;
            const float4* g = (const float4*)(src + (size_t)((i0 + il) * 64 + oo) * stride + base8);
            float4 A = g[0], B = g[1];
            float4* d = (float4*)&wl[(il * 64 + oo) * 8];
            d[0] = A; d[1] = B;
        }
        if (t < 256) {
            int bb = t >> 7, il = (t >> 4) & 7, kk = (t >> 1) & 7, ri = t & 1;
            xl[t] = Xs[((size_t)(((bb * 64 + i0 + il) * 23 + n) * 23 + m) * 8 + kk) * 2 + ri];
        }
        __syncthreads();
#pragma unroll
        for (int il = 0; il < 8; il++) {
            float wv = wl[(il * 64 + o) * 8 + tt];
            float xr0 = xl[(il * 8 + tt) * 2], xi0 = xl[(il * 8 + tt) * 2 + 1];
            float xr1 = xl[128 + (il * 8 + tt) * 2], xi1 = xl[128 + (il * 8 + tt) * 2 + 1];
            aR0 += wv * xr0; aI0 += wv * xi0;
            aR1 += wv * xr1; aI1 += wv * xi1;
        }
        __syncthreads();
    }
    size_t ob0 = ((size_t)((o * 23 + n) * 23 + m) * 8 + tt) * 2;
    size_t ob1 = ((size_t)(((64 + o) * 23 + n) * 23 + m) * 8 + tt) * 2;
    Md[ob0] = aR0; Md[ob0 + 1] = aI0;
    Md[ob1] = aR1; Md[ob1 + 1] = aI1;
}

// ---------------- inverse y (23 -> 64) ----------------
__global__ void k_inv_y(const float* __restrict__ Md, const float* __restrict__ txi,
                        float* __restrict__ T1) {
    int bid = blockIdx.x;
    int b = bid / 1472, rem = bid % 1472, o = rem / 23, m = rem % 23;
    int t = threadIdx.x;
    __shared__ float s[368];  // [n][k][2]
    if (t < 184) {
        int n = t >> 3, kk = t & 7;
        size_t g = ((size_t)(((b * 64 + o) * 23 + n) * 23 + m) * 8 + kk) * 2;
        s[t * 2] = Md[g]; s[t * 2 + 1] = Md[g + 1];
    }
    __syncthreads();
    int y = t >> 3, k = t & 7;
    float sr = 0.f, si = 0.f;
    for (int n = 0; n < 23; n++) {
        float ar = s[(n * 8 + k) * 2], ai = s[(n * 8 + k) * 2 + 1];
        float tr = txi[(y * 23 + n) * 2], ti = txi[(y * 23 + n) * 2 + 1];
        sr += ar * tr - ai * ti;
        si += ar * ti + ai * tr;
    }
    size_t g = ((size_t)(((b * 64 + o) * 64 + y) * 23 + m) * 8 + k) * 2;
    T1[g] = sr; T1[g + 1] = si;
}

// ---------------- inverse x (23 -> 64) ----------------
__global__ void k_inv_x(const float* __restrict__ T1, const float* __restrict__ txi,
                        float* __restrict__ T2) {
    int bid = blockIdx.x;
    int b = bid >> 12, o = (bid >> 6) & 63, y = bid & 63;
    int t = threadIdx.x;
    __shared__ float s[368];  // [m][k][2]
    if (t < 184) {
        size_t g = (size_t)(((b * 64 + o) * 64 + y)) * 368 + t * 2;
        s[t * 2] = T1[g]; s[t * 2 + 1] = T1[g + 1];
    }
    __syncthreads();
    int xx = t >> 3, k = t & 7;
    float sr = 0.f, si = 0.f;
    for (int m = 0; m < 23; m++) {
        float ar = s[(m * 8 + k) * 2], ai = s[(m * 8 + k) * 2 + 1];
        float tr = txi[(xx * 23 + m) * 2], ti = txi[(xx * 23 + m) * 2 + 1];
        sr += ar * tr - ai * ti;
        si += ar * ti + ai * tr;
    }
    size_t g = ((size_t)((b * 64 + o) * 4096 + y * 64 + xx) * 8 + k) * 2;
    T2[g] = sr; T2[g + 1] = si;
}

// ---------------- inline erf-based GELU (no OCML call; A&S 7.1.26, |err|<=1.5e-7) ----
__device__ __forceinline__ float gelu_fast(float x) {
    float u = x * 0.70710678118654752f;
    float a = fabsf(u);
    float t = 1.0f / (1.0f + 0.3275911f * a);
    float poly = t * (0.254829592f + t * (-0.284496736f + t * (1.421413741f +
                 t * (-1.453152027f + t * 1.061405429f))));
    float erfa = 1.0f - poly * __expf(-a * a);
    float er = copysignf(erfa, u);
    return 0.5f * x * (1.0f + er);
}

// ---------------- mlp1: c2r inverse-z + GEMM1 + gelu -> g[j][P] ----------------
// grid (b,y,xg) = 1024 blocks, 320 threads = 8 cols x 40 z.
// Per-thread live set: x1[64] + ~20 temps (~85 VGPR) — fits any budget, no spill.
__global__ __launch_bounds__(320, 2) void k_mlp1(
    const float* __restrict__ t2buf, const float* __restrict__ w1,
    const float* __restrict__ b1, const float* __restrict__ tzi,
    float* __restrict__ g) {
    int bid = blockIdx.x;
    int b = bid >> 9, y = (bid >> 3) & 63, xg = bid & 7;
    int t = threadIdx.x;
    int col = t / 40, z = t % 40;
    __shared__ __align__(16) float t2s[8 * 1028];
    size_t gbase = (size_t)b * 4194304 + (size_t)(y * 64 + xg * 8) * 16;
    for (int idx = t; idx < 2048; idx += 320) {
        int o = idx >> 5, cl = (idx >> 2) & 7, q = idx & 3;
        const float4* gp = (const float4*)(t2buf + gbase + (size_t)o * 65536 + cl * 16 + q * 4);
        *(float4*)&t2s[cl * 1028 + o * 16 + q * 4] = *gp;
    }
    __syncthreads();
    float ck1 = tzi[(z * 8 + 1) * 2], sk1 = tzi[(z * 8 + 1) * 2 + 1];
    float ck2 = tzi[(z * 8 + 2) * 2], sk2 = tzi[(z * 8 + 2) * 2 + 1];
    float ck3 = tzi[(z * 8 + 3) * 2], sk3 = tzi[(z * 8 + 3) * 2 + 1];
    float ck4 = tzi[(z * 8 + 4) * 2], sk4 = tzi[(z * 8 + 4) * 2 + 1];
    float ck5 = tzi[(z * 8 + 5) * 2], sk5 = tzi[(z * 8 + 5) * 2 + 1];
    float ck6 = tzi[(z * 8 + 6) * 2], sk6 = tzi[(z * 8 + 6) * 2 + 1];
    float ck7 = tzi[(z * 8 + 7) * 2], sk7 = tzi[(z * 8 + 7) * 2 + 1];
    const float scale = 1.0f / 163840.0f;
    float x1[64];
    const int tboff = col * 1028;
#pragma unroll 64
    for (int i = 0; i < 64; i++) {
        float4 r0 = *(const float4*)&t2s[tboff + i * 16];
        float4 r1 = *(const float4*)&t2s[tboff + i * 16 + 4];
        float4 r2 = *(const float4*)&t2s[tboff + i * 16 + 8];
        float4 r3 = *(const float4*)&t2s[tboff + i * 16 + 12];
        float acc = r0.x;  // Im of DC dropped (pocketfft c2r)
        acc += 2.0f * (r0.z * ck1 - r0.w * sk1);
        acc += 2.0f * (r1.x * ck2 - r1.y * sk2);
        acc += 2.0f * (r1.z * ck3 - r1.w * sk3);
        acc += 2.0f * (r2.x * ck4 - r2.y * sk4);
        acc += 2.0f * (r2.z * ck5 - r2.w * sk5);
        acc += 2.0f * (r3.x * ck6 - r3.y * sk6);
        acc += 2.0f * (r3.z * ck7 - r3.w * sk7);
        x1[i] = acc * scale;
    }
    size_t P = (size_t)b * 163840 + (size_t)(y * 64 + xg * 8) * 40 + col * 40 + z;
#pragma unroll 2
    for (int j = 0; j < 64; j++) {
        float hj = b1[j];
#pragma unroll 64
        for (int i = 0; i < 64; i++) hj += w1[j * 64 + i] * x1[i];
        g[(size_t)j * 327680 + P] = gelu_fast(hj);
    }
}

// ---------------- mlp2: GEMM2 + skip + relu, IN-PLACE on x ----------------
// One thread owns one point's full channel column -> in-place is race-free.
// Per-thread live set: outv[64] + ~15 temps (~80 VGPR).
__global__ __launch_bounds__(256, 2) void k_mlp2(
    const float* __restrict__ g, float* __restrict__ x,
    const float* __restrict__ w2t, const float* __restrict__ b2,
    const float* __restrict__ wwt, const float* __restrict__ wb, int dorelu) {
    int gid = blockIdx.x * 256 + threadIdx.x;  // 327680
    int b = gid / 163840, p = gid % 163840;
    size_t colbase = (size_t)b * 10485760 + p;
    float outv[64];
#pragma unroll 64
    for (int o = 0; o < 64; o++) outv[o] = b2[o] + wb[o];
#pragma unroll 2
    for (int j = 0; j < 64; j++) {
        float gj = g[(size_t)j * 327680 + gid];
#pragma unroll 64
        for (int o = 0; o < 64; o++) outv[o] += w2t[j * 64 + o] * gj;
    }
#pragma unroll 2
    for (int i = 0; i < 64; i++) {
        float xi = x[colbase + (size_t)i * 163840];
#pragma unroll 64
        for (int o = 0; o < 64; o++) outv[o] += wwt[i * 64 + o] * xi;
    }
#pragma unroll 64
    for (int o = 0; o < 64; o++) {
        float v = outv[o];
        if (dorelu) v = fmaxf(v, 0.0f);
        x[colbase + (size_t)o * 163840] = v;
    }
}

// ---------------- final head: mlp3d with q weights ----------------
__global__ __launch_bounds__(256, 2) void k_head(
    const float* __restrict__ xcur,
    const float* __restrict__ qw1, const float* __restrict__ qb1,
    const float* __restrict__ qw2, const float* __restrict__ qb2,
    float* __restrict__ outp) {
    int gid = blockIdx.x * 256 + threadIdx.x;  // 327680
    int b = gid / 163840, p = gid % 163840;
    float xv[64];
    size_t base = (size_t)b * 10485760 + p;
#pragma unroll 64
    for (int i = 0; i < 64; i++) xv[i] = xcur[base + (size_t)i * 163840];
    float acc = qb2[0];
    for (int j = 0; j < 256; j++) {
        float h = qb1[j];
#pragma unroll 64
        for (int i = 0; i < 64; i++) h += qw1[j * 64 + i] * xv[i];
        acc += qw2[j] * gelu_fast(h);
    }
    outp[gid] = acc;
}

extern "C" void kernel_launch(void* const* d_in, const int* in_sizes, int n_in,
                              void* d_out, int out_size, void* d_ws, size_t ws_size,
                              hipStream_t stream) {
    const float* x_in = (const float*)d_in[0];
    const float* p_w  = (const float*)d_in[1];
    const float* p_b  = (const float*)d_in[2];
    const float* W_LC = (const float*)d_in[3];
    const float* W_LR = (const float*)d_in[4];
    const float* m_w1 = (const float*)d_in[5];
    const float* m_b1 = (const float*)d_in[6];
    const float* m_w2 = (const float*)d_in[7];
    const float* m_b2 = (const float*)d_in[8];
    const float* w_w  = (const float*)d_in[9];
    const float* w_b  = (const float*)d_in[10];
    const float* q_w1 = (const float*)d_in[11];
    const float* q_b1 = (const float*)d_in[12];
    const float* q_w2 = (const float*)d_in[13];
    const float* q_b2 = (const float*)d_in[14];

    char* ws = (char*)d_ws;
    float* tzf = (float*)(ws + 0);
    float* tzi = (float*)(ws + 4096);
    float* txf = (float*)(ws + 8192);
    float* txi = (float*)(ws + 20480);
    float* w2t = (float*)(ws + 32768);
    float* wwt = (float*)(ws + 32768 + 65536);
    size_t off = 32768 + 131072;
    float* xA = (float*)(ws + off); off += 83886080ull;
    float* gbuf = (float*)(ws + off); off += 83886080ull;   // g[j][P], 64*327680*4
    float* Fx = (float*)(ws + off); off += 12058624ull;
    float* Xs = (float*)(ws + off); off += 4333568ull;
    float* Md = (float*)(ws + off); off += 4333568ull;
    float* T1 = (float*)(ws + off); off += 12058624ull;
    float* T2 = (float*)(ws + off); off += 33554432ull;

    k_tables<<<6, 256, 0, stream>>>(tzf, tzi, txf, txi);
    k_wtrans<<<64, 256, 0, stream>>>(m_w2, w_w, w2t, wwt);
    k_lift<<<1280, 256, 0, stream>>>(x_in, p_w, p_b, xA);

    for (int l = 0; l < 4; l++) {
        k_fwd_zx<<<8192, 256, 0, stream>>>(xA, tzf, txf, Fx);
        k_fwd_y<<<2944, 192, 0, stream>>>(Fx, txf, Xs);
        k_mix<<<529, 512, 0, stream>>>(Xs, W_LC + (size_t)l * 393216,
                                       W_LR + (size_t)l * 3964928, Md);
        k_inv_y<<<2944, 512, 0, stream>>>(Md, txi, T1);
        k_inv_x<<<8192, 512, 0, stream>>>(T1, txi, T2);
        k_mlp1<<<1024, 320, 0, stream>>>(T2, m_w1 + (size_t)l * 4096, m_b1 + l * 64,
                                         tzi, gbuf);
        k_mlp2<<<1280, 256, 0, stream>>>(gbuf, xA, w2t + (size_t)l * 4096, m_b2 + l * 64,
                                         wwt + (size_t)l * 4096, w_b + l * 64,
                                         (l < 3) ? 1 : 0);
    }
    k_head<<<1280, 256, 0, stream>>>(xA, q_w1, q_b1, q_w2, q_b2, (float*)d_out);
}